// Round 8
// baseline (4750.996 us; speedup 1.0000x reference)
//
#include <hip/hip_runtime.h>
#include <hip/hip_fp16.h>
#include <math.h>

#define H 2048
#define T 8
#define NSTEP 24
#define NBLK 512
#define NTHR 256
#define LOFF ((size_t)4 * H * H)   // elements per layer per weight tensor

__device__ __forceinline__ float sigmoidf_(float x) { return 1.0f / (1.0f + expf(-x)); }

// dot of 8 fp16 weights (packed in a float4) with 8 fp32 activations (2 float4s)
__device__ __forceinline__ float dot8(float4 w8, const float4 xa, const float4 xb) {
    const __half2* h = reinterpret_cast<const __half2*>(&w8);
    float2 f0 = __half22float2(h[0]);
    float2 f1 = __half22float2(h[1]);
    float2 f2 = __half22float2(h[2]);
    float2 f3 = __half22float2(h[3]);
    return f0.x * xa.x + f0.y * xa.y + f1.x * xa.z + f1.y * xa.w +
           f2.x * xb.x + f2.y * xb.y + f3.x * xb.z + f3.y * xb.w;
}

__global__ void init_ctrl(int* ctrl) { ctrl[0] = 0; ctrl[1] = 0; }

// Device-scope grid barrier (all NBLK blocks co-resident: 512 blocks / 256 CUs).
__device__ __forceinline__ void grid_barrier(int* bar, int* gen) {
    __syncthreads();
    if (threadIdx.x == 0) {
        __threadfence();  // release: prior writes device-visible
        int g = __hip_atomic_load(gen, __ATOMIC_ACQUIRE, __HIP_MEMORY_SCOPE_AGENT);
        int a = __hip_atomic_fetch_add(bar, 1, __ATOMIC_ACQ_REL, __HIP_MEMORY_SCOPE_AGENT);
        if (a == NBLK - 1) {
            __hip_atomic_store(bar, 0, __ATOMIC_RELAXED, __HIP_MEMORY_SCOPE_AGENT);
            __threadfence();
            __hip_atomic_fetch_add(gen, 1, __ATOMIC_RELEASE, __HIP_MEMORY_SCOPE_AGENT);
        } else {
            while (__hip_atomic_load(gen, __ATOMIC_RELAXED, __HIP_MEMORY_SCOPE_AGENT) == g)
                __builtin_amdgcn_s_sleep(1);
        }
        __threadfence();  // acquire: subsequent reads see fresh data
    }
    __syncthreads();
}

// ws layout (bytes):
//   [0,8)        : bar, gen (ints)
//   [1024, ...)  : part_g  = NBLK*8 floats (16 KB)
//   [64K, 64K+32K): h0A, h0B, h1A, h1B  (each H floats = 8 KB)
//   [128K, ...)  : wih_h (2*LOFF halfs, 67.1 MB), whh_h (67.1 MB)
__global__ __launch_bounds__(NTHR) void arch_sampler(
    const float* __restrict__ g_emb, const float* __restrict__ w_emb,
    const float* __restrict__ w_soft, const float* __restrict__ w_ih,
    const float* __restrict__ w_hh, const float* __restrict__ u,
    float* __restrict__ out, char* __restrict__ wsb) {
    int* bar = (int*)wsb;
    int* gen = bar + 1;
    float* part_g = (float*)(wsb + 1024);
    float* h0b[2] = {(float*)(wsb + (64 << 10)), (float*)(wsb + (64 << 10) + H * 4)};
    float* h1b[2] = {(float*)(wsb + (64 << 10) + 2 * H * 4), (float*)(wsb + (64 << 10) + 3 * H * 4)};
    __half* wih_h = (__half*)(wsb + (128 << 10));
    __half* whh_h = wih_h + 2 * LOFF;

    const int tid = threadIdx.x;
    const int lane = tid & 63;
    const int wv = tid >> 6;
    const int j = blockIdx.x * 4 + wv;
    const int gtid = blockIdx.x * NTHR + tid;
    const int gstride = NBLK * NTHR;

    // ---- prologue: fp32 -> fp16 weight conversion + state zeroing ----
    {
        const int n8 = (int)(2 * LOFF / 8);
        const float4* s4 = reinterpret_cast<const float4*>(w_ih);
        float4* d4 = reinterpret_cast<float4*>(wih_h);
        for (int i = gtid; i < n8; i += gstride) {
            float4 a = s4[2 * i], b = s4[2 * i + 1];
            union { __half2 h[4]; float4 f; } o;
            o.h[0] = __floats2half2_rn(a.x, a.y);
            o.h[1] = __floats2half2_rn(a.z, a.w);
            o.h[2] = __floats2half2_rn(b.x, b.y);
            o.h[3] = __floats2half2_rn(b.z, b.w);
            d4[i] = o.f;
        }
        s4 = reinterpret_cast<const float4*>(w_hh);
        d4 = reinterpret_cast<float4*>(whh_h);
        for (int i = gtid; i < n8; i += gstride) {
            float4 a = s4[2 * i], b = s4[2 * i + 1];
            union { __half2 h[4]; float4 f; } o;
            o.h[0] = __floats2half2_rn(a.x, a.y);
            o.h[1] = __floats2half2_rn(a.z, a.w);
            o.h[2] = __floats2half2_rn(b.x, b.y);
            o.h[3] = __floats2half2_rn(b.z, b.w);
            d4[i] = o.f;
        }
        for (int i = gtid; i < H; i += gstride) { h0b[0][i] = 0.f; h1b[0][i] = 0.f; }
    }
    grid_barrier(bar, gen);

    __shared__ float lds_part[4][8];
    __shared__ int s_best;

    const float* xptr = g_emb;
    int pa = 0, pb = 0;
    float c0r = 0.f, c1r = 0.f;
    float xent = 0.f;

    for (int s = 0; s < NSTEP; ++s) {
        // ---------- phase A: layer-0 cell for this wave's j ----------
        {
            const float4* x4 = reinterpret_cast<const float4*>(xptr);
            const float4* h4 = reinterpret_cast<const float4*>(h0b[pa]);
            const float4* wi0 = reinterpret_cast<const float4*>(wih_h + (size_t)(0 * H + j) * H);
            const float4* wi1 = reinterpret_cast<const float4*>(wih_h + (size_t)(1 * H + j) * H);
            const float4* wi2 = reinterpret_cast<const float4*>(wih_h + (size_t)(2 * H + j) * H);
            const float4* wi3 = reinterpret_cast<const float4*>(wih_h + (size_t)(3 * H + j) * H);
            const float4* wh0 = reinterpret_cast<const float4*>(whh_h + (size_t)(0 * H + j) * H);
            const float4* wh1 = reinterpret_cast<const float4*>(whh_h + (size_t)(1 * H + j) * H);
            const float4* wh2 = reinterpret_cast<const float4*>(whh_h + (size_t)(2 * H + j) * H);
            const float4* wh3 = reinterpret_cast<const float4*>(whh_h + (size_t)(3 * H + j) * H);
            float a0 = 0.f, a1 = 0.f, a2 = 0.f, a3 = 0.f;
#pragma unroll
            for (int kk = lane; kk < H / 8; kk += 64) {
                float4 xa = x4[2 * kk], xb = x4[2 * kk + 1];
                float4 ha = h4[2 * kk], hb = h4[2 * kk + 1];
                a0 += dot8(wi0[kk], xa, xb) + dot8(wh0[kk], ha, hb);
                a1 += dot8(wi1[kk], xa, xb) + dot8(wh1[kk], ha, hb);
                a2 += dot8(wi2[kk], xa, xb) + dot8(wh2[kk], ha, hb);
                a3 += dot8(wi3[kk], xa, xb) + dot8(wh3[kk], ha, hb);
            }
#pragma unroll
            for (int off = 1; off < 64; off <<= 1) {
                a0 += __shfl_xor(a0, off, 64);
                a1 += __shfl_xor(a1, off, 64);
                a2 += __shfl_xor(a2, off, 64);
                a3 += __shfl_xor(a3, off, 64);
            }
            float c2 = sigmoidf_(a1) * c0r + sigmoidf_(a0) * tanhf(a2);
            float h2 = sigmoidf_(a3) * tanhf(c2);
            c0r = c2;
            if (lane == 0) h0b[pa ^ 1][j] = h2;
        }
        grid_barrier(bar, gen);
        pa ^= 1;

        // ---------- phase B: layer-1 cell + per-block logit partials ----------
        {
            const float4* x4 = reinterpret_cast<const float4*>(h0b[pa]);
            const float4* h4 = reinterpret_cast<const float4*>(h1b[pb]);
            const __half* wiL = wih_h + LOFF;
            const __half* whL = whh_h + LOFF;
            const float4* wi0 = reinterpret_cast<const float4*>(wiL + (size_t)(0 * H + j) * H);
            const float4* wi1 = reinterpret_cast<const float4*>(wiL + (size_t)(1 * H + j) * H);
            const float4* wi2 = reinterpret_cast<const float4*>(wiL + (size_t)(2 * H + j) * H);
            const float4* wi3 = reinterpret_cast<const float4*>(wiL + (size_t)(3 * H + j) * H);
            const float4* wh0 = reinterpret_cast<const float4*>(whL + (size_t)(0 * H + j) * H);
            const float4* wh1 = reinterpret_cast<const float4*>(whL + (size_t)(1 * H + j) * H);
            const float4* wh2 = reinterpret_cast<const float4*>(whL + (size_t)(2 * H + j) * H);
            const float4* wh3 = reinterpret_cast<const float4*>(whL + (size_t)(3 * H + j) * H);
            float a0 = 0.f, a1 = 0.f, a2 = 0.f, a3 = 0.f;
#pragma unroll
            for (int kk = lane; kk < H / 8; kk += 64) {
                float4 xa = x4[2 * kk], xb = x4[2 * kk + 1];
                float4 ha = h4[2 * kk], hb = h4[2 * kk + 1];
                a0 += dot8(wi0[kk], xa, xb) + dot8(wh0[kk], ha, hb);
                a1 += dot8(wi1[kk], xa, xb) + dot8(wh1[kk], ha, hb);
                a2 += dot8(wi2[kk], xa, xb) + dot8(wh2[kk], ha, hb);
                a3 += dot8(wi3[kk], xa, xb) + dot8(wh3[kk], ha, hb);
            }
#pragma unroll
            for (int off = 1; off < 64; off <<= 1) {
                a0 += __shfl_xor(a0, off, 64);
                a1 += __shfl_xor(a1, off, 64);
                a2 += __shfl_xor(a2, off, 64);
                a3 += __shfl_xor(a3, off, 64);
            }
            float c2 = sigmoidf_(a1) * c1r + sigmoidf_(a0) * tanhf(a2);
            float h2 = sigmoidf_(a3) * tanhf(c2);
            c1r = c2;
            if (lane == 0) h1b[pb ^ 1][j] = h2;
            if (lane < 8) lds_part[wv][lane] = h2 * w_soft[(size_t)j * T + lane];
        }
        pb ^= 1;
        __syncthreads();
        if (tid < 8)
            part_g[blockIdx.x * 8 + tid] =
                lds_part[0][tid] + lds_part[1][tid] + lds_part[2][tid] + lds_part[3][tid];
        grid_barrier(bar, gen);

        // ---------- phase C: redundant deterministic sample on wave 0 ----------
        if (wv == 0) {
            const int t = lane & 7;
            const int cch = lane >> 3;  // 8 chunks of 64 blocks
            float acc = 0.f;
            const int b0 = cch * 64;
            for (int b = b0; b < b0 + 64; ++b) acc += part_g[b * 8 + t];
            acc += __shfl_xor(acc, 8, 64);
            acc += __shfl_xor(acc, 16, 64);
            acc += __shfl_xor(acc, 32, 64);
            const float lv = acc;  // logit[t]
            float m = lv;
            m = fmaxf(m, __shfl_xor(m, 1, 64));
            m = fmaxf(m, __shfl_xor(m, 2, 64));
            m = fmaxf(m, __shfl_xor(m, 4, 64));
            float se = expf(lv - m);
            se += __shfl_xor(se, 1, 64);
            se += __shfl_xor(se, 2, 64);
            se += __shfl_xor(se, 4, 64);
            const float lse = m + logf(se);
            const float uu = u[s * T + t];
            float v = lv - lse - logf(-logf(uu));
            int bi = t;
#pragma unroll
            for (int off = 1; off < 8; off <<= 1) {
                float ov = __shfl_xor(v, off, 64);
                int oi = __shfl_xor(bi, off, 64);
                if (ov > v || (ov == v && oi < bi)) { v = ov; bi = oi; }
            }
            const float lpb = __shfl(lv, bi, 64) - lse;
            if (tid == 0) {
                xent += -lpb;
                if (blockIdx.x == 0) {
                    out[s] = (float)bi;
                    if (s == NSTEP - 1) out[NSTEP] = xent / (float)NSTEP;
                }
                s_best = bi;
            }
        }
        __syncthreads();
        xptr = w_emb + ((size_t)s * T + s_best) * H;
    }
}

extern "C" void kernel_launch(void* const* d_in, const int* in_sizes, int n_in,
                              void* d_out, int out_size, void* d_ws, size_t ws_size,
                              hipStream_t stream) {
    const float* g_emb  = (const float*)d_in[0];
    const float* w_emb  = (const float*)d_in[1];
    const float* w_soft = (const float*)d_in[2];
    const float* w_ih   = (const float*)d_in[3];
    const float* w_hh   = (const float*)d_in[4];
    const float* u      = (const float*)d_in[5];

    init_ctrl<<<dim3(1), dim3(1), 0, stream>>>((int*)d_ws);
    arch_sampler<<<dim3(NBLK), dim3(NTHR), 0, stream>>>(
        g_emb, w_emb, w_soft, w_ih, w_hh, u, (float*)d_out, (char*)d_ws);
}

// Round 11
// 1199.437 us; speedup vs baseline: 3.9610x; 3.9610x over previous
//
#include <hip/hip_runtime.h>
#include <hip/hip_fp16.h>
#include <math.h>

#define H 2048
#define T 8
#define NSTEP 24
#define NBLK 256
#define NTHR 512
#define NGRP 8
#define GRPSZ (NBLK / NGRP)        // 32 blocks per group
#define LOFF ((size_t)4 * H * H)   // elements per layer per weight tensor

__device__ __forceinline__ float sigmoidf_(float x) { return 1.0f / (1.0f + expf(-x)); }

// dot of 8 fp16 weights (packed in a float4) with 8 fp32 activations (2 float4s)
__device__ __forceinline__ float dot8(float4 w8, const float4 xa, const float4 xb) {
    const __half2* h = reinterpret_cast<const __half2*>(&w8);
    float2 f0 = __half22float2(h[0]);
    float2 f1 = __half22float2(h[1]);
    float2 f2 = __half22float2(h[2]);
    float2 f3 = __half22float2(h[3]);
    return f0.x * xa.x + f0.y * xa.y + f1.x * xa.z + f1.y * xa.w +
           f2.x * xb.x + f2.y * xb.y + f3.x * xb.z + f3.y * xb.w;
}

__global__ void init_ctrl(int* ctrl) {
    // zero first 4 KB (gen @0, root @256B, grp[i] @512+256i B)
    int i = threadIdx.x;
    if (i < 1024) ctrl[i] = 0;
}

// Hierarchical device-scope grid barrier.
// Contention: 32 RELEASE-adds per group line (8 lines in parallel) + 8 on root.
// Cache maintenance: writeback on release-add; ONE acquire (invalidate) per
// block per barrier after spin exit. Spin is RELAXED (no cache ops).
// Spin is BOUNDED (~14 ms) so a protocol bug degrades to a wrong answer
// instead of a container-killing hang; normal waits are ~µs.
__device__ __forceinline__ void grid_barrier(char* wsb, int grp) {
    __syncthreads();
    if (threadIdx.x == 0) {
        int* gen  = (int*)wsb;
        int* root = (int*)(wsb + 256);
        int* gcnt = (int*)(wsb + 512 + 256 * grp);
        int g = __hip_atomic_load(gen, __ATOMIC_RELAXED, __HIP_MEMORY_SCOPE_AGENT);
        int a = __hip_atomic_fetch_add(gcnt, 1, __ATOMIC_RELEASE, __HIP_MEMORY_SCOPE_AGENT);
        if (a == GRPSZ - 1) {
            // all group members arrived; reset is published by the release root-add
            __hip_atomic_store(gcnt, 0, __ATOMIC_RELAXED, __HIP_MEMORY_SCOPE_AGENT);
            int r = __hip_atomic_fetch_add(root, 1, __ATOMIC_ACQ_REL, __HIP_MEMORY_SCOPE_AGENT);
            if (r == NGRP - 1) {
                __hip_atomic_store(root, 0, __ATOMIC_RELAXED, __HIP_MEMORY_SCOPE_AGENT);
                __hip_atomic_fetch_add(gen, 1, __ATOMIC_RELEASE, __HIP_MEMORY_SCOPE_AGENT);
            }
        }
        int spin = 0;
        while (__hip_atomic_load(gen, __ATOMIC_RELAXED, __HIP_MEMORY_SCOPE_AGENT) == g &&
               spin < (1 << 18)) {
            __builtin_amdgcn_s_sleep(2);
            ++spin;
        }
        (void)__hip_atomic_load(gen, __ATOMIC_ACQUIRE, __HIP_MEMORY_SCOPE_AGENT);
    }
    __syncthreads();
}

// ws layout (bytes):
//   [0, 4K)        : barrier state (gen, root, 8 group counters; 256B-spaced)
//   [4K, 12K)      : part_g = NBLK*8 floats
//   [64K, 96K)     : h0A, h0B, h1A, h1B (each H floats = 8 KB)
//   [128K, ...)    : wih_h (2*LOFF halfs, 67.1 MB), whh_h (67.1 MB)
__global__ __launch_bounds__(NTHR) void arch_sampler(
    const float* __restrict__ g_emb, const float* __restrict__ w_emb,
    const float* __restrict__ w_soft, const float* __restrict__ w_ih,
    const float* __restrict__ w_hh, const float* __restrict__ u,
    float* __restrict__ out, char* __restrict__ wsb) {
    float* part_g = (float*)(wsb + 4096);
    float* h0b[2] = {(float*)(wsb + (64 << 10)), (float*)(wsb + (64 << 10) + H * 4)};
    float* h1b[2] = {(float*)(wsb + (64 << 10) + 2 * H * 4), (float*)(wsb + (64 << 10) + 3 * H * 4)};
    __half* wih_h = (__half*)(wsb + (128 << 10));
    __half* whh_h = wih_h + 2 * LOFF;

    const int tid = threadIdx.x;
    const int lane = tid & 63;
    const int wv = tid >> 6;                 // 8 waves
    const int j = blockIdx.x * 8 + wv;       // owned row, 256*8 = 2048 = H
    const int grp = blockIdx.x >> 5;         // 8 groups of 32 blocks
    const int gtid = blockIdx.x * NTHR + tid;
    const int gstride = NBLK * NTHR;

    // ---- prologue: fp32 -> fp16 weight conversion + state zeroing ----
    {
        const int n8 = (int)(2 * LOFF / 8);
        const float4* s4 = reinterpret_cast<const float4*>(w_ih);
        float4* d4 = reinterpret_cast<float4*>(wih_h);
        for (int i = gtid; i < n8; i += gstride) {
            float4 a = s4[2 * i], b = s4[2 * i + 1];
            union { __half2 h[4]; float4 f; } o;
            o.h[0] = __floats2half2_rn(a.x, a.y);
            o.h[1] = __floats2half2_rn(a.z, a.w);
            o.h[2] = __floats2half2_rn(b.x, b.y);
            o.h[3] = __floats2half2_rn(b.z, b.w);
            d4[i] = o.f;
        }
        s4 = reinterpret_cast<const float4*>(w_hh);
        d4 = reinterpret_cast<float4*>(whh_h);
        for (int i = gtid; i < n8; i += gstride) {
            float4 a = s4[2 * i], b = s4[2 * i + 1];
            union { __half2 h[4]; float4 f; } o;
            o.h[0] = __floats2half2_rn(a.x, a.y);
            o.h[1] = __floats2half2_rn(a.z, a.w);
            o.h[2] = __floats2half2_rn(b.x, b.y);
            o.h[3] = __floats2half2_rn(b.z, b.w);
            d4[i] = o.f;
        }
        for (int i = gtid; i < H; i += gstride) { h0b[0][i] = 0.f; h1b[0][i] = 0.f; }
    }
    grid_barrier(wsb, grp);

    __shared__ float lds_part[8][8];
    __shared__ int s_best;

    const float* xptr = g_emb;
    int pa = 0, pb = 0;
    float c0r = 0.f, c1r = 0.f;
    float xent = 0.f;

    for (int s = 0; s < NSTEP; ++s) {
        // ---------- phase A: layer-0 cell for this wave's j ----------
        {
            const float4* x4 = reinterpret_cast<const float4*>(xptr);
            const float4* h4 = reinterpret_cast<const float4*>(h0b[pa]);
            const float4* wi0 = reinterpret_cast<const float4*>(wih_h + (size_t)(0 * H + j) * H);
            const float4* wi1 = reinterpret_cast<const float4*>(wih_h + (size_t)(1 * H + j) * H);
            const float4* wi2 = reinterpret_cast<const float4*>(wih_h + (size_t)(2 * H + j) * H);
            const float4* wi3 = reinterpret_cast<const float4*>(wih_h + (size_t)(3 * H + j) * H);
            const float4* wh0 = reinterpret_cast<const float4*>(whh_h + (size_t)(0 * H + j) * H);
            const float4* wh1 = reinterpret_cast<const float4*>(whh_h + (size_t)(1 * H + j) * H);
            const float4* wh2 = reinterpret_cast<const float4*>(whh_h + (size_t)(2 * H + j) * H);
            const float4* wh3 = reinterpret_cast<const float4*>(whh_h + (size_t)(3 * H + j) * H);
            float a0 = 0.f, a1 = 0.f, a2 = 0.f, a3 = 0.f;
#pragma unroll
            for (int kk = lane; kk < H / 8; kk += 64) {
                float4 xa = x4[2 * kk], xb = x4[2 * kk + 1];
                float4 ha = h4[2 * kk], hb = h4[2 * kk + 1];
                a0 += dot8(wi0[kk], xa, xb) + dot8(wh0[kk], ha, hb);
                a1 += dot8(wi1[kk], xa, xb) + dot8(wh1[kk], ha, hb);
                a2 += dot8(wi2[kk], xa, xb) + dot8(wh2[kk], ha, hb);
                a3 += dot8(wi3[kk], xa, xb) + dot8(wh3[kk], ha, hb);
            }
#pragma unroll
            for (int off = 1; off < 64; off <<= 1) {
                a0 += __shfl_xor(a0, off, 64);
                a1 += __shfl_xor(a1, off, 64);
                a2 += __shfl_xor(a2, off, 64);
                a3 += __shfl_xor(a3, off, 64);
            }
            float c2 = sigmoidf_(a1) * c0r + sigmoidf_(a0) * tanhf(a2);
            float h2 = sigmoidf_(a3) * tanhf(c2);
            c0r = c2;
            if (lane == 0) h0b[pa ^ 1][j] = h2;
        }
        grid_barrier(wsb, grp);
        pa ^= 1;

        // ---------- phase B: layer-1 cell + per-block logit partials ----------
        {
            const float4* x4 = reinterpret_cast<const float4*>(h0b[pa]);
            const float4* h4 = reinterpret_cast<const float4*>(h1b[pb]);
            const __half* wiL = wih_h + LOFF;
            const __half* whL = whh_h + LOFF;
            const float4* wi0 = reinterpret_cast<const float4*>(wiL + (size_t)(0 * H + j) * H);
            const float4* wi1 = reinterpret_cast<const float4*>(wiL + (size_t)(1 * H + j) * H);
            const float4* wi2 = reinterpret_cast<const float4*>(wiL + (size_t)(2 * H + j) * H);
            const float4* wi3 = reinterpret_cast<const float4*>(wiL + (size_t)(3 * H + j) * H);
            const float4* wh0 = reinterpret_cast<const float4*>(whL + (size_t)(0 * H + j) * H);
            const float4* wh1 = reinterpret_cast<const float4*>(whL + (size_t)(1 * H + j) * H);
            const float4* wh2 = reinterpret_cast<const float4*>(whL + (size_t)(2 * H + j) * H);
            const float4* wh3 = reinterpret_cast<const float4*>(whL + (size_t)(3 * H + j) * H);
            float a0 = 0.f, a1 = 0.f, a2 = 0.f, a3 = 0.f;
#pragma unroll
            for (int kk = lane; kk < H / 8; kk += 64) {
                float4 xa = x4[2 * kk], xb = x4[2 * kk + 1];
                float4 ha = h4[2 * kk], hb = h4[2 * kk + 1];
                a0 += dot8(wi0[kk], xa, xb) + dot8(wh0[kk], ha, hb);
                a1 += dot8(wi1[kk], xa, xb) + dot8(wh1[kk], ha, hb);
                a2 += dot8(wi2[kk], xa, xb) + dot8(wh2[kk], ha, hb);
                a3 += dot8(wi3[kk], xa, xb) + dot8(wh3[kk], ha, hb);
            }
#pragma unroll
            for (int off = 1; off < 64; off <<= 1) {
                a0 += __shfl_xor(a0, off, 64);
                a1 += __shfl_xor(a1, off, 64);
                a2 += __shfl_xor(a2, off, 64);
                a3 += __shfl_xor(a3, off, 64);
            }
            float c2 = sigmoidf_(a1) * c1r + sigmoidf_(a0) * tanhf(a2);
            float h2 = sigmoidf_(a3) * tanhf(c2);
            c1r = c2;
            if (lane == 0) h1b[pb ^ 1][j] = h2;
            if (lane < 8) lds_part[wv][lane] = h2 * w_soft[(size_t)j * T + lane];
        }
        pb ^= 1;
        __syncthreads();
        if (tid < 8) {
            float p = 0.f;
#pragma unroll
            for (int w = 0; w < 8; ++w) p += lds_part[w][tid];
            part_g[blockIdx.x * 8 + tid] = p;
        }
        grid_barrier(wsb, grp);

        // ---------- phase C: redundant deterministic sample on wave 0 ----------
        if (wv == 0) {
            const int t = lane & 7;
            const int cch = lane >> 3;  // 8 chunks of 32 blocks
            float acc = 0.f;
            const int b0 = cch * 32;
            for (int b = b0; b < b0 + 32; ++b) acc += part_g[b * 8 + t];
            acc += __shfl_xor(acc, 8, 64);
            acc += __shfl_xor(acc, 16, 64);
            acc += __shfl_xor(acc, 32, 64);
            const float lv = acc;  // logit[t]
            float m = lv;
            m = fmaxf(m, __shfl_xor(m, 1, 64));
            m = fmaxf(m, __shfl_xor(m, 2, 64));
            m = fmaxf(m, __shfl_xor(m, 4, 64));
            float se = expf(lv - m);
            se += __shfl_xor(se, 1, 64);
            se += __shfl_xor(se, 2, 64);
            se += __shfl_xor(se, 4, 64);
            const float lse = m + logf(se);
            const float uu = u[s * T + t];
            float v = lv - lse - logf(-logf(uu));
            int bi = t;
#pragma unroll
            for (int off = 1; off < 8; off <<= 1) {
                float ov = __shfl_xor(v, off, 64);
                int oi = __shfl_xor(bi, off, 64);
                if (ov > v || (ov == v && oi < bi)) { v = ov; bi = oi; }
            }
            const float lpb = __shfl(lv, bi, 64) - lse;
            if (tid == 0) {
                xent += -lpb;
                if (blockIdx.x == 0) {
                    out[s] = (float)bi;
                    if (s == NSTEP - 1) out[NSTEP] = xent / (float)NSTEP;
                }
                s_best = bi;
            }
        }
        __syncthreads();
        xptr = w_emb + ((size_t)s * T + s_best) * H;
    }
}

extern "C" void kernel_launch(void* const* d_in, const int* in_sizes, int n_in,
                              void* d_out, int out_size, void* d_ws, size_t ws_size,
                              hipStream_t stream) {
    const float* g_emb  = (const float*)d_in[0];
    const float* w_emb  = (const float*)d_in[1];
    const float* w_soft = (const float*)d_in[2];
    const float* w_ih   = (const float*)d_in[3];
    const float* w_hh   = (const float*)d_in[4];
    const float* u      = (const float*)d_in[5];

    init_ctrl<<<dim3(1), dim3(1024), 0, stream>>>((int*)d_ws);
    arch_sampler<<<dim3(NBLK), dim3(NTHR), 0, stream>>>(
        g_emb, w_emb, w_soft, w_ih, w_hh, u, (float*)d_out, (char*)d_ws);
}